// Round 1
// baseline (457.080 us; speedup 1.0000x reference)
//
#include <hip/hip_runtime.h>

// EventMessagePassingEdge: per-edge 2-layer MLP with gathered node features.
//   evt[e] = [h[src[e]], e_h[e], h[dst[e]]]           (192 fp32)
//   x      = evt @ W1 + b1                            (64)
//   out    = relu([x, ext[e]] @ W2 + b2)              (64 fp32)
// Strategy: bf16 MFMA 16x16x32. Per wave: 16-edge tile.
//   Layer1: A = evt tile [16x192], B = W1 [192x64]  -> 6 kc x 4 ntile MFMAs
//   Layer2: A = [x, ext] [16x96],  B = W2 [96x64]   -> 3 kc x 4 ntile MFMAs
// W1/W2 staged once per block in LDS in B-fragment order (conflict-free b128).
// evt/x2 staged per wave in A-fragment order. No __syncthreads in main loop.

typedef __attribute__((ext_vector_type(8))) short bf16x8;
typedef __attribute__((ext_vector_type(4))) float f32x4;

__device__ __forceinline__ short f2bf(float f) {
  // round-to-nearest-even fp32 -> bf16
  unsigned u = __builtin_bit_cast(unsigned, f);
  u = (u + 0x7FFFu + ((u >> 16) & 1u)) >> 16;
  return (short)u;
}

// LDS layout (shorts):
//   [0,     12288)  W1 frags: slot s = (kc*4+nt)*64 + lane, 8 bf16 each
//   [12288, 18432)  W2 frags: slot s = (kc*4+nt)*64 + lane, 8 bf16 each
//   [18432, 30720)  per-wave evt/x2 region, 3072 shorts (6144 B) per wave
//     evt  slot = kc*64 + quad*16 + m   (kc 0..5)  holds evt[m][kc*32+quad*8+j]
//     x2 reuses same region (kc 0..2) after layer-1 A reads are done.

__global__ __launch_bounds__(256, 2) void edge_mp_kernel(
    const float* __restrict__ h, const float* __restrict__ e_h,
    const float* __restrict__ ext, const float* __restrict__ W1,
    const float* __restrict__ b1, const float* __restrict__ W2,
    const float* __restrict__ b2, const int* __restrict__ src,
    const int* __restrict__ dst, float* __restrict__ out, int E) {
  __shared__ __align__(16) short lds[30720];
  const int tid = threadIdx.x;
  const int l = tid & 63;          // lane
  const int wid = tid >> 6;        // wave in block
  const int i = l & 15;            // MFMA idx (col of C, row of A)
  const int q = l >> 4;            // MFMA quad
  const int i2 = l >> 2;           // staging: edge within tile
  const int c = l & 3;             // staging: chunk lane

  // ---- stage W1 fragments (1536 slots) ----
  for (int s = tid; s < 1536; s += 256) {
    int kc = s >> 8, nt = (s >> 6) & 3, ll = s & 63;
    int k0 = kc * 32 + ((ll >> 4) * 8), n = nt * 16 + (ll & 15);
#pragma unroll
    for (int j = 0; j < 8; ++j) lds[s * 8 + j] = f2bf(W1[(k0 + j) * 64 + n]);
  }
  // ---- stage W2 fragments (768 slots) ----
  for (int s = tid; s < 768; s += 256) {
    int kc = s >> 8, nt = (s >> 6) & 3, ll = s & 63;
    int k0 = kc * 32 + ((ll >> 4) * 8), n = nt * 16 + (ll & 15);
#pragma unroll
    for (int j = 0; j < 8; ++j)
      lds[12288 + s * 8 + j] = f2bf(W2[(k0 + j) * 64 + n]);
  }
  __syncthreads();

  float b1v[4], b2v[4];
#pragma unroll
  for (int nt = 0; nt < 4; ++nt) {
    b1v[nt] = b1[nt * 16 + i];
    b2v[nt] = b2[nt * 16 + i];
  }

  short* evt = &lds[18432 + wid * 3072];

  for (int it = 0; it < 4; ++it) {
    const int e0 = blockIdx.x * 256 + it * 64 + wid * 16;
    if (e0 >= E) break;
    int e = e0 + i2;
    if (e >= E) e = E - 1;
    const int sI = src[e], dI = dst[e];
    const float* srcp[3] = {h + (size_t)sI * 64, e_h + (size_t)e * 64,
                            h + (size_t)dI * 64};

    // ---- gather evt tile -> A-fragment-order LDS (bf16) ----
    // lane (i2,c): per source, 4 iters t; float4 at offset 16t+4c (64B-coalesced)
#pragma unroll
    for (int s = 0; s < 3; ++s) {
#pragma unroll
      for (int t = 0; t < 4; ++t) {
        const int k0 = 16 * t + 4 * c;
        float4 v = *(const float4*)(srcp[s] + k0);
        const int kc = s * 2 + (t >> 1);
        const int quad = 2 * (t & 1) + (c >> 1);
        const int j0 = 4 * (c & 1);
        short4 p;
        p.x = f2bf(v.x); p.y = f2bf(v.y); p.z = f2bf(v.z); p.w = f2bf(v.w);
        *(short4*)&evt[(kc * 64 + quad * 16 + i2) * 8 + j0] = p;
      }
    }

    // ---- layer 1: 6 kc x 4 ntile MFMAs ----
    f32x4 acc[4] = {{0.f, 0.f, 0.f, 0.f},
                    {0.f, 0.f, 0.f, 0.f},
                    {0.f, 0.f, 0.f, 0.f},
                    {0.f, 0.f, 0.f, 0.f}};
#pragma unroll
    for (int kc = 0; kc < 6; ++kc) {
      bf16x8 a = *(const bf16x8*)&evt[(kc * 64 + l) * 8];
#pragma unroll
      for (int nt = 0; nt < 4; ++nt) {
        bf16x8 b = *(const bf16x8*)&lds[((kc * 4 + nt) * 64 + l) * 8];
        acc[nt] = __builtin_amdgcn_mfma_f32_16x16x32_bf16(a, b, acc[nt], 0, 0, 0);
      }
    }

    // ---- x (C-layout) + b1 -> bf16 -> x2 A-layout in LDS (m120 round-trip) ----
#pragma unroll
    for (int nt = 0; nt < 4; ++nt) {
      const int n = nt * 16 + i;
      const int kc2 = n >> 5, qA = (n & 31) >> 3, j = n & 7;
#pragma unroll
      for (int r = 0; r < 4; ++r) {
        const int m = q * 4 + r;  // C row = edge within tile
        evt[(kc2 * 64 + qA * 16 + m) * 8 + j] = f2bf(acc[nt][r] + b1v[nt]);
      }
    }
    // ---- ext -> x2 chunk kc2 = 2 ----
#pragma unroll
    for (int t = 0; t < 2; ++t) {
      float4 v = *(const float4*)(ext + (size_t)e * 32 + 16 * t + 4 * c);
      const int quad = 2 * t + (c >> 1);
      const int j0 = 4 * (c & 1);
      short4 p;
      p.x = f2bf(v.x); p.y = f2bf(v.y); p.z = f2bf(v.z); p.w = f2bf(v.w);
      *(short4*)&evt[(2 * 64 + quad * 16 + i2) * 8 + j0] = p;
    }

    // ---- layer 2: 3 kc x 4 ntile MFMAs ----
    f32x4 acc2[4] = {{0.f, 0.f, 0.f, 0.f},
                     {0.f, 0.f, 0.f, 0.f},
                     {0.f, 0.f, 0.f, 0.f},
                     {0.f, 0.f, 0.f, 0.f}};
#pragma unroll
    for (int kc = 0; kc < 3; ++kc) {
      bf16x8 a = *(const bf16x8*)&evt[(kc * 64 + l) * 8];
#pragma unroll
      for (int nt = 0; nt < 4; ++nt) {
        bf16x8 b = *(const bf16x8*)&lds[12288 + ((kc * 4 + nt) * 64 + l) * 8];
        acc2[nt] =
            __builtin_amdgcn_mfma_f32_16x16x32_bf16(a, b, acc2[nt], 0, 0, 0);
      }
    }

    // ---- epilogue: +b2, relu, store fp32 (C-layout) ----
#pragma unroll
    for (int nt = 0; nt < 4; ++nt) {
      const int n = nt * 16 + i;
#pragma unroll
      for (int r = 0; r < 4; ++r) {
        const int er = e0 + q * 4 + r;
        if (er < E) {
          float v = acc2[nt][r] + b2v[nt];
          out[(size_t)er * 64 + n] = fmaxf(v, 0.f);
        }
      }
    }
  }
}

extern "C" void kernel_launch(void* const* d_in, const int* in_sizes, int n_in,
                              void* d_out, int out_size, void* d_ws,
                              size_t ws_size, hipStream_t stream) {
  const float* h = (const float*)d_in[0];
  const float* e_h = (const float*)d_in[1];
  const float* ext = (const float*)d_in[2];
  const float* W1 = (const float*)d_in[3];
  const float* b1 = (const float*)d_in[4];
  const float* W2 = (const float*)d_in[5];
  const float* b2 = (const float*)d_in[6];
  const int* src = (const int*)d_in[7];
  const int* dst = (const int*)d_in[8];
  float* out = (float*)d_out;
  const int E = in_sizes[7];  // 800000
  const int blocks = (E + 255) / 256;
  hipLaunchKernelGGL(edge_mp_kernel, dim3(blocks), dim3(256), 0, stream, h, e_h,
                     ext, W1, b1, W2, b2, src, dst, out, E);
}